// Round 1
// baseline (293.038 us; speedup 1.0000x reference)
//
#include <hip/hip_runtime.h>

#define NXD 512
#define NYD 512
#define CD  64
#define NPIX (NXD * NYD)
// Problem constants fixed by the reference: B=4, C=64, NX=NY=512.
//
// Window decomposition (R5, measured via rocprof): harness poisons the 1 GiB
// workspace (166-172 us @ 6.3 TB/s) + 268 MB output (~42 us) INSIDE the timed
// window => ~210 us fixed. Our kernels ~79 us vs ~50 us floor. Optimize only
// the kernel-side share; compare kernel dispatch times, not headline dur_us.
//
// Round-3 lesson (measured): per-instruction 16B/lane contiguous stores +
// linear block-order streams are mandatory (R3's 1 MiB-strided channel sweep
// regressed 79->155 us). R5 keeps both invariants: the second quad per thread
// is at t + 2^23 (same pixel/channel, batch b+2) -> two fully-coalesced
// linear streams, 2x MLP on the winner->feat dependent chain.
//
// Round-4 lesson: __builtin_nontemporal_store needs a NATIVE vector type,
// not HIP's float4 class. Use ext_vector_type(4).

typedef float nfloat4 __attribute__((ext_vector_type(4)));

// Init winner array to -1 (int4 stores). 4 MiB.
__global__ void ppscatter_init_winner(int4* __restrict__ win4, int n_win4) {
    int i = blockIdx.x * blockDim.x + threadIdx.x;
    if (i < n_win4) win4[i] = make_int4(-1, -1, -1, -1);
}

// Last-write-wins vote: max voxel index per flat slot wins (matches numpy
// fancy-assignment last-duplicate-wins; verified absmax=0.0 rounds 1-4).
__global__ void ppscatter_vote(const int* __restrict__ coords, int n,
                               int* __restrict__ winner) {
    int v = blockIdx.x * blockDim.x + threadIdx.x;
    if (v >= n) return;
    int b = coords[3 * v + 0];
    int x = coords[3 * v + 1];
    int y = coords[3 * v + 2];
    atomicMax(&winner[b * NPIX + x * NYD + y], v);
}

// Gather v2: one thread per TWO output float4s, split across the batch dim.
//   t bits: y4 [0:6], x [7:15], c [16:21], b_lo [22]   (8,388,608 threads)
//   quad0 = out4[t]            (batch b_lo,   pixel pix, channel c)
//   quad1 = out4[t + 2^23]     (batch b_lo+2, same pixel, same channel)
// Each store instruction remains 64 lanes x 16 B contiguous (1 KB), and the
// two streams are linear in block order. Both winner int4 loads are issued
// back-to-back before any consumer -> one vmcnt wait covers both (2x MLP).
// Stores are NON-TEMPORAL so the 268 MB write stream doesn't evict winner
// (4 MB) and feat (20 MB) from L2 -- re-read across the 64 channel sweeps.
__global__ void __launch_bounds__(256)
ppscatter_gather(const float* __restrict__ feat,
                 const int* __restrict__ winner,
                 nfloat4* __restrict__ out4) {
    int t = blockIdx.x * blockDim.x + threadIdx.x;  // 8,388,608 threads
    int c   = (t >> 16) & 63;
    int pix = t & 0xFFFF;                           // quad index within plane
    int b0  = t >> 22;                              // 0 or 1

    const int4* win4 = (const int4*)winner;
    int wi = (b0 << 16) | pix;
    int4 w0 = win4[wi];                             // batch b0
    int4 w1 = win4[wi + (2 << 16)];                 // batch b0+2

    nfloat4 v0 = {0.f, 0.f, 0.f, 0.f};
    nfloat4 v1 = {0.f, 0.f, 0.f, 0.f};
    // Empty fast path: entries are -1 or >=0; AND == -1 iff all empty (~74%).
    if ((w0.x & w0.y & w0.z & w0.w) != -1) {
        if (w0.x >= 0) v0.x = feat[(w0.x << 6) + c];
        if (w0.y >= 0) v0.y = feat[(w0.y << 6) + c];
        if (w0.z >= 0) v0.z = feat[(w0.z << 6) + c];
        if (w0.w >= 0) v0.w = feat[(w0.w << 6) + c];
    }
    if ((w1.x & w1.y & w1.z & w1.w) != -1) {
        if (w1.x >= 0) v1.x = feat[(w1.x << 6) + c];
        if (w1.y >= 0) v1.y = feat[(w1.y << 6) + c];
        if (w1.z >= 0) v1.z = feat[(w1.z << 6) + c];
        if (w1.w >= 0) v1.w = feat[(w1.w << 6) + c];
    }
    __builtin_nontemporal_store(v0, &out4[t]);
    __builtin_nontemporal_store(v1, &out4[t + (1 << 23)]);
}

extern "C" void kernel_launch(void* const* d_in, const int* in_sizes, int n_in,
                              void* d_out, int out_size, void* d_ws, size_t ws_size,
                              hipStream_t stream) {
    const float* feat  = (const float*)d_in[0];
    const int* coords  = (const int*)d_in[1];

    int n = in_sizes[1] / 3;            // 80000 voxels
    int* winner = (int*)d_ws;           // B*NX*NY ints = 4 MiB scratch

    const int T = 256;
    int B = out_size / (CD * NPIX);     // 4

    int n_win4 = (B * NPIX) / 4;        // 262144
    ppscatter_init_winner<<<(n_win4 + T - 1) / T, T, 0, stream>>>((int4*)winner, n_win4);

    ppscatter_vote<<<(n + T - 1) / T, T, 0, stream>>>(coords, n, winner);

    int n_thr = out_size / 4 / 2;       // 8,388,608 threads (2 quads each)
    ppscatter_gather<<<n_thr / T, T, 0, stream>>>(feat, winner, (nfloat4*)d_out);
}